// Round 8
// baseline (54.494 us; speedup 1.0000x reference)
//
#include <hip/hip_runtime.h>
#include <hip/hip_bf16.h>

// CAM: out = (q @ k^T) @ v + v  ==  q @ (k^T @ v) + v.   S[b] = k^T v is 49x49.
// Pure-bf16 MFMA (RNE), barrier-free streaming:
//   ktv : NO LDS, 1 MFMA/chunk. A[i][c]=K[c][i], B[c][j]=V[c][j] read as
//         lane-consecutive coalesced global loads; zero barriers.
//   sred: sum split partials -> St = S^T in bf16, zero-padded [64][64]/batch.
//   qs  : NO LDS, no barrier. A = q rows direct from global (L1-resident),
//         B = St bf16x8 single 16-B load (L2-hot). 4 MFMA; masked m=48 tail.
// Error budget: pure bf16 RNE adds ~1-2 sigma (~6-12 abs) vs threshold 27.68;
// fp32-baseline absmax floor is 4.0 (R1). C/D map HW-validated by R7 pass.

#define BATCH  128
#define CH     1024
#define NN     49

typedef short  bf16x8 __attribute__((ext_vector_type(8)));
typedef float  f32x16 __attribute__((ext_vector_type(16)));

__device__ __forceinline__ short f2bf(float x) {
  return __builtin_bit_cast(short, __float2bfloat16(x));   // RNE; pairs to cvt_pk
}

// ---------------- Kernel 1: Spart[b*split+s] = K-chunk^T @ V-chunk ----------
__global__ __launch_bounds__(256) void ktv_kernel(
    const float* __restrict__ Kg, const float* __restrict__ Vg,
    float* __restrict__ Spart, int split, int nchunks) {
  const int blk  = blockIdx.x;
  const int b    = blk / split;
  const int s    = blk - b * split;
  const int tid  = threadIdx.x;
  const int wv   = tid >> 6;
  const int lane = tid & 63;
  const int g    = lane >> 5;
  const int ln   = lane & 31;
  const int i0   = (wv >> 1) * 32;
  const int j0   = (wv & 1)  * 32;
  const int rowA = min(i0 + ln, NN - 1);   // clamp: dup loads, rows discarded
  const int rowB = min(j0 + ln, NN - 1);

  const size_t cbase = ((size_t)b * CH + (size_t)s * (nchunks * 16)) * NN;
  const float* Ka = Kg + cbase + (size_t)(g * 8) * NN + rowA;
  const float* Vb = Vg + cbase + (size_t)(g * 8) * NN + rowB;

  f32x16 acc;
  #pragma unroll
  for (int r = 0; r < 16; ++r) acc[r] = 0.f;

  #pragma unroll 2
  for (int kc = 0; kc < nchunks; ++kc) {
    const float* ka = Ka + (size_t)kc * 16 * NN;
    const float* vb = Vb + (size_t)kc * 16 * NN;
    float kx[8], vx[8];
    #pragma unroll
    for (int e = 0; e < 8; ++e) { kx[e] = ka[e * NN]; vx[e] = vb[e * NN]; }
    bf16x8 ah, bh;
    #pragma unroll
    for (int e = 0; e < 8; ++e) { ah[e] = f2bf(kx[e]); bh[e] = f2bf(vx[e]); }
    acc = __builtin_amdgcn_mfma_f32_32x32x16_bf16(ah, bh, acc, 0, 0, 0);
  }

  // C/D: col = lane&31, row = (r&3) + 8*(r>>2) + 4*(lane>>5)   [m74/m101]
  float* Sp = Spart + (size_t)blk * (NN * NN);
  const int j = j0 + ln;
  if (j < NN) {
    #pragma unroll
    for (int r = 0; r < 16; ++r) {
      const int i = i0 + (r & 3) + 8 * (r >> 2) + 4 * g;
      if (i < NN) Sp[i * NN + j] = acc[r];
    }
  }
}

// ------- Kernel 2: St[b][n][m] = bf16( sum_s Spart[m][n] ), [64][64] pad ----
__global__ __launch_bounds__(256) void sred_kernel(
    const float* __restrict__ Spart, unsigned short* __restrict__ St, int split) {
  const int b = blockIdx.x;
  const int t = threadIdx.x;
  for (int e = t; e < 64 * 64; e += 256) {
    const int n = e >> 6, m = e & 63;
    float v = 0.f;
    if (m < NN && n < NN) {
      for (int s = 0; s < split; ++s)
        v += Spart[(size_t)(b * split + s) * (NN * NN) + m * NN + n];
    }
    St[(size_t)b * 4096 + e] = (unsigned short)f2bf(v);
  }
}

// ---------------- Kernel 3: out[64-row tile] = q @ S + v  (MFMA) ------------
// A = q rows direct from global (8 consecutive f32/lane, L1-resident tile);
// B = St bf16x8, one 16-B load per chunk (L2-hot). No LDS, no barriers.
__global__ __launch_bounds__(256) void qs_kernel(
    const float* __restrict__ Qg, const float* __restrict__ Vg,
    const unsigned short* __restrict__ St, float* __restrict__ Og) {
  const int blk  = blockIdx.x;            // 2048 = 128 batches x 16 row-tiles
  const int b    = blk >> 4;
  const int rt   = blk & 15;
  const int tid  = threadIdx.x;
  const int wv   = tid >> 6;
  const int lane = tid & 63;
  const int g    = lane >> 5;
  const int ln   = lane & 31;
  const int i0   = (wv >> 1) * 32;
  const int j0   = (wv & 1)  * 32;

  const size_t qbase = ((size_t)b * CH + (size_t)rt * 64) * NN;
  const int rowA = i0 + ln;               // 0..63, all valid (rows = channels)
  const int colB = min(j0 + ln, NN - 1);  // clamp; junk cols discarded

  const float* qa = Qg + qbase + (size_t)rowA * NN;
  const unsigned short* Stb = St + (size_t)b * 4096 + colB * 64;

  f32x16 acc;
  #pragma unroll
  for (int r = 0; r < 16; ++r) acc[r] = 0.f;

  #pragma unroll
  for (int kc = 0; kc < 3; ++kc) {        // m0 <= 47: all 8 m's valid
    const int m0 = kc * 16 + g * 8;
    bf16x8 ah;
    #pragma unroll
    for (int e = 0; e < 8; ++e) ah[e] = f2bf(qa[m0 + e]);
    const bf16x8 bh = *(const bf16x8*)&Stb[m0];       // 16-B aligned, zero-pad
    acc = __builtin_amdgcn_mfma_f32_32x32x16_bf16(ah, bh, acc, 0, 0, 0);
  }
  {                                        // tail chunk: only m=48 is real
    const int m0 = 48 + g * 8;
    bf16x8 ah;
    #pragma unroll
    for (int e = 0; e < 8; ++e) ah[e] = 0;
    if (g == 0) ah[0] = f2bf(qa[48]);
    const bf16x8 bh = *(const bf16x8*)&Stb[m0];       // zeros beyond m=48
    acc = __builtin_amdgcn_mfma_f32_32x32x16_bf16(ah, bh, acc, 0, 0, 0);
  }

  // store: all 64 rows valid; guard only col j < 49. Coalesced per r.
  const int j = j0 + ln;
  if (j < NN) {
    #pragma unroll
    for (int r = 0; r < 16; ++r) {
      const int i = i0 + (r & 3) + 8 * (r >> 2) + 4 * g;
      const size_t off = qbase + (size_t)i * NN + j;
      Og[off] = acc[r] + Vg[off];
    }
  }
}

extern "C" void kernel_launch(void* const* d_in, const int* in_sizes, int n_in,
                              void* d_out, int out_size, void* d_ws, size_t ws_size,
                              hipStream_t stream) {
  (void)in_sizes; (void)n_in; (void)out_size;
  const float* v1 = (const float*)d_in[0];
  const float* q1 = (const float*)d_in[1];
  const float* k1 = (const float*)d_in[2];
  float* out = (float*)d_out;

  int split = 8;                           // 9.83 MB spart + 1.05 MB St
  while (split > 1 &&
         (size_t)BATCH * split * NN * NN * 4 + (size_t)BATCH * 4096 * 2 > ws_size)
    split >>= 1;
  const int nchunks = CH / (split * 16);

  float* spart = (float*)d_ws;
  unsigned short* st = (unsigned short*)(spart + (size_t)BATCH * split * NN * NN);

  ktv_kernel<<<dim3(BATCH * split), dim3(256), 0, stream>>>(k1, v1, spart, split, nchunks);
  sred_kernel<<<dim3(BATCH), dim3(256), 0, stream>>>(spart, st, split);
  qs_kernel<<<dim3(BATCH * 16), dim3(256), 0, stream>>>(q1, v1, st, out);
}